// Round 10
// baseline (228.131 us; speedup 1.0000x reference)
//
#include <hip/hip_runtime.h>
#include <hip/hip_bf16.h>

typedef __attribute__((ext_vector_type(8))) short short8;
typedef __attribute__((ext_vector_type(4))) float f32x4;

#define NDIM 1024
#define INDIM 1024
#define KEXP 8
#define BROWS 8192
#define NX (BROWS * INDIM)        // x elements        8388608
#define NW (KEXP * NDIM * INDIM)  // w elements        8388608
#define NPH (BROWS * NDIM)        // partial elems     8388608
#define EWEPS 1e-20f

__device__ __forceinline__ unsigned int pack2bf(float a, float b) {
    __hip_bfloat162 h = __float22bfloat162_rn(make_float2(a, b));
    union { __hip_bfloat162 h; unsigned int u; } cv;
    cv.h = h;
    return cv.u;
}

__device__ __forceinline__ float bf2f(unsigned short u) {
    return __uint_as_float(((unsigned int)u) << 16);
}

__device__ __forceinline__ void gload16(const void* src, void* ldsdst) {
    __builtin_amdgcn_global_load_lds(
        (__attribute__((address_space(1))) void*)(src),
        (__attribute__((address_space(3))) void*)(ldsdst), 16, 0, 0);
}

// convert: dst = [bf16(x) | bf16(w)] contiguous (used by both paths)
__global__ void convert_bf16(const float* __restrict__ x, const float* __restrict__ w,
                             unsigned short* __restrict__ dst) {
    const long total = (long)NX + NW;
    const long stride = (long)gridDim.x * blockDim.x * 8;
    for (long i = ((long)blockIdx.x * blockDim.x + threadIdx.x) * 8; i < total; i += stride) {
        const float* s = (i < NX) ? (x + i) : (w + (i - NX));
        float4 a = ((const float4*)s)[0];
        float4 b = ((const float4*)s)[1];
        uint4 q;
        q.x = pack2bf(a.x, a.y); q.y = pack2bf(a.z, a.w);
        q.z = pack2bf(b.x, b.y); q.w = pack2bf(b.z, b.w);
        *(uint4*)(dst + i) = q;
    }
}

// ============================ path A (ws >= 67.2 MB) ============================
// r5's winning GEMM (BM=BN=256, BK=64, 8 waves of 128x64, dbuf-2, vmcnt(0) gates)
// reading UNSCALED bf16 x as A (L3-hot, no A' buffer). Routing weights folded in
// via the accumulator-rescale invariant: acc = (sum_{k<=j} e'_k P_k)/e'_j,
// rescaled by e'_j/e'_{j+1} at the 3 expert boundaries, * e'_last in epilogue.
__global__ __launch_bounds__(512, 2)
void moe_gemm_rs(const unsigned short* __restrict__ Xb,   // [8192][1024] bf16
                 const float* __restrict__ ew,            // [8192][8]
                 const unsigned short* __restrict__ Wp,   // [8][1024][1024] bf16
                 unsigned short* __restrict__ Pp) {       // [2][8192][1024] partials
    __shared__ __align__(16) unsigned short lds[2 * 32768];   // 128 KiB dbuf

    const int tid = threadIdx.x;
    const int bid = blockIdx.x;
    const int comp = bid & 7;          // (nt,h) == XCD: W panel (2 MB) L2-pinned
    const int nt = comp >> 1;          // 0..3
    const int h  = comp & 1;           // K half (experts 0-3 / 4-7)
    const int mt = bid >> 3;           // 0..31
    const int mbase = mt * 256;
    const int nbase = nt * 256;
    const int kofs = h * 4096;

    const int w  = tid >> 6;           // wave 0..7 (2M x 4N), wave tile 128x64
    const int l  = tid & 63;
    const int lr = l & 15;
    const int lg = l >> 4;
    const int wrow = (w >> 2) * 128;
    const int wcol = (w & 3) * 64;

    // staging lane coords: chunk = 16 rows x 32 cols bf16 = 1024 B
    const int lrow = l >> 2;
    const int sg = (l & 3) ^ ((l >> 3) & 3);     // pre-swizzled col block (involution)
    const int swz = (lr >> 1) & 3;

    // fragment read offsets (ushort units), matching XOR involution
    int aoff[8][2], boff[4][2];
#pragma unroll
    for (int mf = 0; mf < 8; ++mf)
#pragma unroll
        for (int ks = 0; ks < 2; ++ks)
            aoff[mf][ks] = ks * 8192 + (wrow + mf * 16 + lr) * 32 + ((lg ^ swz) * 8);
#pragma unroll
    for (int nf = 0; nf < 4; ++nf)
#pragma unroll
        for (int ks = 0; ks < 2; ++ks)
            boff[nf][ks] = 16384 + ks * 8192 + (wcol + nf * 16 + lr) * 32 + ((lg ^ swz) * 8);

    // clamped routing weights for this wave's 32 output rows, current expert
    float er[8][4];
#pragma unroll
    for (int mf = 0; mf < 8; ++mf)
#pragma unroll
        for (int j = 0; j < 4; ++j)
            er[mf][j] = fmaxf(ew[(size_t)(mbase + wrow + mf * 16 + lg * 4 + j) * KEXP + h * 4], EWEPS);

    // staging: 64 chunks/tile (A ids 0-31, B ids 32-63), wave w owns ids w*8..w*8+7
    auto stage4 = [&](int slot, int kt, int half) {
#pragma unroll
        for (int i = 0; i < 4; ++i) {
            const int id = w * 8 + half * 4 + i;
            unsigned short* dst = &lds[slot * 32768 + id * 512];
            const int ks = (id >> 4) & 1;
            const int sub = id & 15;
            const int kcb = kofs + kt * 64 + ks * 32 + sg * 8;   // global contraction col
            if (id < 32) {
                // A = unscaled x: x-column is contraction col mod 1024
                gload16(Xb + (size_t)(mbase + sub * 16 + lrow) * INDIM + (kcb & 1023), dst);
            } else {
                gload16(Wp + (size_t)(kcb >> 10) * (NDIM * INDIM)
                           + (size_t)(nbase + sub * 16 + lrow) * INDIM + (kcb & 1023), dst);
            }
        }
    };

    f32x4 acc[8][4];
#pragma unroll
    for (int mf = 0; mf < 8; ++mf)
#pragma unroll
        for (int nf = 0; nf < 4; ++nf) acc[mf][nf] = f32x4{0.f, 0.f, 0.f, 0.f};

    stage4(0, 0, 0);
    stage4(0, 0, 1);

#pragma unroll 1
    for (int kt = 0; kt < 64; ++kt) {
        const int cs = kt & 1;
        const bool doS = (kt + 1) < 64;

        // tile gate: stage(kt) landed; barrier publishes all waves' staging.
        asm volatile("s_waitcnt vmcnt(0)\n\ts_barrier" ::: "memory");

        // expert boundary: acc *= e'_prev / e'_next (per output row), exact f32
        if ((kt & 15) == 0 && kt != 0) {
            const int en_idx = h * 4 + (kt >> 4);
#pragma unroll
            for (int mf = 0; mf < 8; ++mf)
#pragma unroll
                for (int j = 0; j < 4; ++j) {
                    const float en = fmaxf(
                        ew[(size_t)(mbase + wrow + mf * 16 + lg * 4 + j) * KEXP + en_idx], EWEPS);
                    const float rr = er[mf][j] / en;
                    er[mf][j] = en;
#pragma unroll
                    for (int nf = 0; nf < 4; ++nf) acc[mf][nf][j] *= rr;
                }
        }

        const unsigned short* lb = &lds[cs * 32768];
        short8 alo[4], ahi[4], b0[4], b1[4];

        // q0 operands + first staging batch + q1 A-frags (drain under q0 MFMA)
#pragma unroll
        for (int m = 0; m < 4; ++m) alo[m] = *(const short8*)(lb + aoff[m][0]);
#pragma unroll
        for (int n = 0; n < 4; ++n) b0[n] = *(const short8*)(lb + boff[n][0]);
        if (doS) stage4(cs ^ 1, kt + 1, 0);
#pragma unroll
        for (int m = 0; m < 4; ++m) ahi[m] = *(const short8*)(lb + aoff[4 + m][0]);

        __builtin_amdgcn_s_setprio(1);
#pragma unroll
        for (int m = 0; m < 4; ++m)
#pragma unroll
            for (int n = 0; n < 4; ++n)
                acc[m][n] = __builtin_amdgcn_mfma_f32_16x16x32_bf16(alo[m], b0[n], acc[m][n], 0, 0, 0);
        __builtin_amdgcn_s_setprio(0);

        // q2 operands (ks1) issued now; second staging batch
#pragma unroll
        for (int n = 0; n < 4; ++n) b1[n] = *(const short8*)(lb + boff[n][1]);
#pragma unroll
        for (int m = 0; m < 4; ++m) alo[m] = *(const short8*)(lb + aoff[m][1]);
        if (doS) stage4(cs ^ 1, kt + 1, 1);

        __builtin_amdgcn_s_setprio(1);
#pragma unroll
        for (int m = 0; m < 4; ++m)
#pragma unroll
            for (int n = 0; n < 4; ++n)
                acc[4 + m][n] = __builtin_amdgcn_mfma_f32_16x16x32_bf16(ahi[m], b0[n], acc[4 + m][n], 0, 0, 0);
        __builtin_amdgcn_s_setprio(0);

#pragma unroll
        for (int m = 0; m < 4; ++m) ahi[m] = *(const short8*)(lb + aoff[4 + m][1]);

        __builtin_amdgcn_s_setprio(1);
#pragma unroll
        for (int m = 0; m < 4; ++m)
#pragma unroll
            for (int n = 0; n < 4; ++n)
                acc[m][n] = __builtin_amdgcn_mfma_f32_16x16x32_bf16(alo[m], b1[n], acc[m][n], 0, 0, 0);
        __builtin_amdgcn_s_setprio(0);

        __builtin_amdgcn_s_setprio(1);
#pragma unroll
        for (int m = 0; m < 4; ++m)
#pragma unroll
            for (int n = 0; n < 4; ++n)
                acc[4 + m][n] = __builtin_amdgcn_mfma_f32_16x16x32_bf16(ahi[m], b1[n], acc[4 + m][n], 0, 0, 0);
        __builtin_amdgcn_s_setprio(0);
    }

    // epilogue: partial = acc * e'_last  -> bf16 store
#pragma unroll
    for (int mf = 0; mf < 8; ++mf)
#pragma unroll
        for (int j = 0; j < 4; ++j) {
            const int grow = mbase + wrow + mf * 16 + lg * 4 + j;
            unsigned short* op = Pp + (size_t)h * NPH + (size_t)grow * NDIM + nbase + wcol;
            const float es = er[mf][j];
#pragma unroll
            for (int nf = 0; nf < 4; ++nf) {
                union { __hip_bfloat16 hh; unsigned short u; } cv;
                cv.hh = __float2bfloat16(acc[mf][nf][j] * es);
                op[nf * 16 + lr] = cv.u;
            }
        }
}

// out = P0 + P1 + ew @ bias   (exact f32 blend of the two K-halves + bias)
__global__ void reduce_blend(const unsigned short* __restrict__ Pp,
                             const float* __restrict__ ew,
                             const float* __restrict__ bias,
                             float* __restrict__ out) {
    const long base = ((long)blockIdx.x * blockDim.x + threadIdx.x) * 8;
    if (base >= NPH) return;
    const int b = (int)(base >> 10);
    const int o = (int)(base & 1023);
    const short8 p0 = *(const short8*)(Pp + base);
    const short8 p1 = *(const short8*)(Pp + NPH + base);
    const float4 ea = *(const float4*)(ew + (size_t)b * KEXP);
    const float4 e2 = *(const float4*)(ew + (size_t)b * KEXP + 4);
    const float e[8] = {ea.x, ea.y, ea.z, ea.w, e2.x, e2.y, e2.z, e2.w};
    float r[8];
#pragma unroll
    for (int j = 0; j < 8; ++j)
        r[j] = bf2f((unsigned short)p0[j]) + bf2f((unsigned short)p1[j]);
#pragma unroll
    for (int k = 0; k < 8; ++k)
#pragma unroll
        for (int j = 0; j < 8; ++j) r[j] += e[k] * bias[k * NDIM + o + j];
    *(float4*)(out + base) = make_float4(r[0], r[1], r[2], r[3]);
    *(float4*)(out + base + 4) = make_float4(r[4], r[5], r[6], r[7]);
}

// ============ path B fallback: round-4 pipeline (ws >= 33.5 MB) ============

#define BM 256
#define BN 128
#define BK 64
#define NT 128
#define ABUF 16384
#define BBUF 8192
#define BUFU (ABUF + BBUF)

__global__ __launch_bounds__(512, 2)
void moe_gemm_pipe(const unsigned short* __restrict__ ab,
                   const float* __restrict__ ew,
                   const float* __restrict__ bias,
                   float* __restrict__ out) {
    __shared__ __align__(16) unsigned short lds[3 * BUFU];

    const int tid = threadIdx.x;
    const int bid = blockIdx.x;
    const int nt = bid & 7;
    const int mt = bid >> 3;
    const int mbase = mt * BM;
    const int nbase = nt * BN;

    const int w  = tid >> 6;
    const int l  = tid & 63;
    const int lr = l & 15;
    const int lg = l >> 4;
    const int wrow = (w >> 1) * 64;
    const int wcol = (w & 1) * 64;

    const int lrow = l >> 2;
    const int sg = (l & 3) ^ ((l >> 3) & 3);

    const unsigned short* Xb = ab;
    const unsigned short* Wb = ab + NX;

    const int swz = (lr >> 1) & 3;
    int aoff[4][2], boff[4][2];
#pragma unroll
    for (int m = 0; m < 4; ++m)
#pragma unroll
        for (int ks = 0; ks < 2; ++ks)
            aoff[m][ks] = ks * 8192 + (wrow + m * 16 + lr) * 32 + ((lg ^ swz) * 8);
#pragma unroll
    for (int n = 0; n < 4; ++n)
#pragma unroll
        for (int ks = 0; ks < 2; ++ks)
            boff[n][ks] = ABUF + ks * 4096 + (wcol + n * 16 + lr) * 32 + ((lg ^ swz) * 8);

    auto stageA = [&](int buf, int kt, int i) {
        const int c = i * 8 + w;
        const int ks = c >> 4, rg = c & 15;
        const unsigned short* src = Xb + (size_t)(mbase + rg * 16 + lrow) * INDIM
                                  + (size_t)((kt & 15) * 64 + ks * 32 + sg * 8);
        gload16(src, &lds[buf * BUFU + c * 512]);
    };
    auto stageB = [&](int buf, int kt, int i) {
        const int c = i * 8 + w;
        const int ks = c >> 3, rg = c & 7;
        const unsigned short* src = Wb + (size_t)(kt >> 4) * (NDIM * INDIM)
                                  + (size_t)(nbase + rg * 16 + lrow) * INDIM
                                  + (size_t)((kt & 15) * 64 + ks * 32 + sg * 8);
        gload16(src, &lds[buf * BUFU + ABUF + c * 512]);
    };

    f32x4 acc[4][4], accT[4][4];
#pragma unroll
    for (int m = 0; m < 4; ++m)
#pragma unroll
        for (int n = 0; n < 4; ++n) {
            acc[m][n] = f32x4{0.f, 0.f, 0.f, 0.f};
            accT[m][n] = f32x4{0.f, 0.f, 0.f, 0.f};
        }

#pragma unroll
    for (int t = 0; t < 2; ++t) {
        stageA(t, t, 0); stageA(t, t, 1); stageA(t, t, 2); stageA(t, t, 3);
        stageB(t, t, 0); stageB(t, t, 1);
    }

    int bufR = 0, bufS = 2;
#pragma unroll 1
    for (int kt = 0; kt < NT; ++kt) {
        const bool doS = (kt + 2) < NT;
        const bool bnd = (kt & 15) == 15;

        if (kt < NT - 2)
            asm volatile("s_waitcnt vmcnt(6)\n\ts_barrier" ::: "memory");
        else
            asm volatile("s_waitcnt vmcnt(0)\n\ts_barrier" ::: "memory");

        float e0[4][4];
        if (bnd) {
            const int eidx = kt >> 4;
#pragma unroll
            for (int m = 0; m < 4; ++m)
#pragma unroll
                for (int j = 0; j < 4; ++j)
                    e0[m][j] = ew[(size_t)(mbase + wrow + m * 16 + lg * 4 + j) * KEXP + eidx];
        }

        const unsigned short* lb = &lds[bufR * BUFU];
        short8 a0[4], b0[4], a1[4], b1[4];
#pragma unroll
        for (int m = 0; m < 4; ++m) a0[m] = *(const short8*)(lb + aoff[m][0]);
#pragma unroll
        for (int n = 0; n < 4; ++n) b0[n] = *(const short8*)(lb + boff[n][0]);
        if (doS) {
            stageA(bufS, kt + 2, 0); stageA(bufS, kt + 2, 1);
            stageA(bufS, kt + 2, 2); stageA(bufS, kt + 2, 3);
            stageB(bufS, kt + 2, 0); stageB(bufS, kt + 2, 1);
        }
#pragma unroll
        for (int m = 0; m < 4; ++m) a1[m] = *(const short8*)(lb + aoff[m][1]);
#pragma unroll
        for (int n = 0; n < 4; ++n) b1[n] = *(const short8*)(lb + boff[n][1]);

        __builtin_amdgcn_s_setprio(1);
#pragma unroll
        for (int m = 0; m < 4; ++m)
#pragma unroll
            for (int n = 0; n < 4; ++n)
                acc[m][n] = __builtin_amdgcn_mfma_f32_16x16x32_bf16(a0[m], b0[n], acc[m][n], 0, 0, 0);
        __builtin_amdgcn_s_setprio(0);
        __builtin_amdgcn_s_setprio(1);
#pragma unroll
        for (int m = 0; m < 4; ++m)
#pragma unroll
            for (int n = 0; n < 4; ++n)
                acc[m][n] = __builtin_amdgcn_mfma_f32_16x16x32_bf16(a1[m], b1[n], acc[m][n], 0, 0, 0);
        __builtin_amdgcn_s_setprio(0);

        if (bnd) {
#pragma unroll
            for (int m = 0; m < 4; ++m)
#pragma unroll
                for (int n = 0; n < 4; ++n) {
#pragma unroll
                    for (int j = 0; j < 4; ++j)
                        accT[m][n][j] += e0[m][j] * acc[m][n][j];
                    acc[m][n] = f32x4{0.f, 0.f, 0.f, 0.f};
                }
        }

        bufR = (bufR == 2) ? 0 : bufR + 1;
        bufS = (bufS == 2) ? 0 : bufS + 1;
    }

    float bv[4][8];
#pragma unroll
    for (int n = 0; n < 4; ++n) {
        const int gc = nbase + wcol + n * 16 + lr;
#pragma unroll
        for (int kk = 0; kk < 8; ++kk) bv[n][kk] = bias[kk * NDIM + gc];
    }
#pragma unroll
    for (int m = 0; m < 4; ++m)
#pragma unroll
        for (int j = 0; j < 4; ++j) {
            const int grow = mbase + wrow + m * 16 + lg * 4 + j;
            const float4* e4 = (const float4*)(ew + (size_t)grow * KEXP);
            const float4 ea = e4[0];
            const float4 eb = e4[1];
            const float ev[8] = {ea.x, ea.y, ea.z, ea.w, eb.x, eb.y, eb.z, eb.w};
            float* op = out + (size_t)grow * NDIM + nbase + wcol;
#pragma unroll
            for (int n = 0; n < 4; ++n) {
                float t = accT[m][n][j];
#pragma unroll
                for (int kk = 0; kk < 8; ++kk) t += ev[kk] * bv[n][kk];
                op[n * 16 + lr] = t;
            }
        }
}

extern "C" void kernel_launch(void* const* d_in, const int* in_sizes, int n_in,
                              void* d_out, int out_size, void* d_ws, size_t ws_size,
                              hipStream_t stream) {
    (void)in_sizes; (void)n_in; (void)out_size;
    const float* x    = (const float*)d_in[0];
    const float* ew   = (const float*)d_in[1];
    const float* w    = (const float*)d_in[2];
    const float* bias = (const float*)d_in[3];
    float* out = (float*)d_out;

    const size_t needA = ((size_t)NX + NW + 2 * (size_t)NPH) * sizeof(unsigned short); // 67.1 MB
    const size_t needB = (size_t)(NX + NW) * sizeof(unsigned short);                   // 33.5 MB

    if (ws_size >= needA) {
        unsigned short* Xb = (unsigned short*)d_ws;
        unsigned short* Wp = Xb + NX;
        unsigned short* Pp = Wp + NW;
        hipLaunchKernelGGL(convert_bf16, dim3(4096), dim3(256), 0, stream, x, w, Xb);
        hipLaunchKernelGGL(moe_gemm_rs, dim3(256), dim3(512), 0, stream, Xb, ew, Wp, Pp);
        hipLaunchKernelGGL(reduce_blend, dim3(4096), dim3(256), 0, stream, Pp, ew, bias, out);
    } else if (ws_size >= needB) {
        unsigned short* ab = (unsigned short*)d_ws;
        hipLaunchKernelGGL(convert_bf16, dim3(4096), dim3(256), 0, stream, x, w, ab);
        hipLaunchKernelGGL(moe_gemm_pipe, dim3(256), dim3(512), 0, stream, ab, ew, bias, out);
    }
}

// Round 11
// 163.073 us; speedup vs baseline: 1.3990x; 1.3990x over previous
//
#include <hip/hip_runtime.h>
#include <hip/hip_bf16.h>

typedef __attribute__((ext_vector_type(8))) short short8;
typedef __attribute__((ext_vector_type(4))) float f32x4;

#define NDIM 1024
#define INDIM 1024
#define KEXP 8
#define BROWS 8192
#define NX (BROWS * INDIM)        // x elements        8388608
#define NW (KEXP * NDIM * INDIM)  // w elements        8388608
#define NA (BROWS * KEXP * INDIM) // A' elements      67108864
#define NPH (BROWS * NDIM)        // partial elems     8388608

__device__ __forceinline__ unsigned int pack2bf(float a, float b) {
    __hip_bfloat162 h = __float22bfloat162_rn(make_float2(a, b));
    union { __hip_bfloat162 h; unsigned int u; } cv;
    cv.h = h;
    return cv.u;
}

__device__ __forceinline__ float bf2f(unsigned short u) {
    return __uint_as_float(((unsigned int)u) << 16);
}

__device__ __forceinline__ void gload16(const void* src, void* ldsdst) {
    __builtin_amdgcn_global_load_lds(
        (__attribute__((address_space(1))) void*)(src),
        (__attribute__((address_space(3))) void*)(ldsdst), 16, 0, 0);
}

// ============================ path A (ws >= 184.5 MB) ============================

// one launch: A'[b][k*1024+i] = bf16(ew[b,k]*x[b,i])  AND  Wp = bf16(w)
__global__ void convert_aw(const float* __restrict__ x, const float* __restrict__ ew,
                           const float* __restrict__ w,
                           unsigned short* __restrict__ Ap, unsigned short* __restrict__ Wp) {
    if (blockIdx.x < 4096) {
        const int t = blockIdx.x * blockDim.x + threadIdx.x;
        const int b = t >> 7;
        const int i0 = (t & 127) * 8;
        const float4 xa = *(const float4*)(x + (size_t)b * INDIM + i0);
        const float4 xb = *(const float4*)(x + (size_t)b * INDIM + i0 + 4);
        const float4 ea = *(const float4*)(ew + (size_t)b * KEXP);
        const float4 e2 = *(const float4*)(ew + (size_t)b * KEXP + 4);
        const float e[8] = {ea.x, ea.y, ea.z, ea.w, e2.x, e2.y, e2.z, e2.w};
        unsigned short* dst = Ap + (size_t)b * (KEXP * INDIM) + i0;
#pragma unroll
        for (int k = 0; k < 8; ++k) {
            const float s = e[k];
            uint4 q;
            q.x = pack2bf(xa.x * s, xa.y * s);
            q.y = pack2bf(xa.z * s, xa.w * s);
            q.z = pack2bf(xb.x * s, xb.y * s);
            q.w = pack2bf(xb.z * s, xb.w * s);
            *(uint4*)(dst + (size_t)k * INDIM) = q;
        }
    } else {
        const long i = ((long)(blockIdx.x - 4096) * blockDim.x + threadIdx.x) * 8;
        if (i >= NW) return;
        const float4 a = ((const float4*)(w + i))[0];
        const float4 b = ((const float4*)(w + i))[1];
        uint4 q;
        q.x = pack2bf(a.x, a.y); q.y = pack2bf(a.z, a.w);
        q.z = pack2bf(b.x, b.y); q.w = pack2bf(b.z, b.w);
        *(uint4*)(Wp + i) = q;
    }
}

// r5's 114µs GEMM with split staging pipelines:
//   A (HBM-slow stream, waves 0-3): ring-3 slots, distance 2, counted vmcnt(8)
//   B (L2-pinned W panel, waves 4-7): dbuf-2, distance 1, vmcnt(0) (free drain)
// LDS = 3*32KB (A) + 2*32KB (B) = 160 KiB exactly. Everything else == r5.
__global__ __launch_bounds__(512, 2)
void moe_gemm_ks4(const unsigned short* __restrict__ Ap,   // [8192][8192]
                  const unsigned short* __restrict__ Wp,   // [8][1024][1024]
                  unsigned short* __restrict__ Pp) {       // [2][8192][1024] partials
    __shared__ __align__(16) unsigned short lds[81920];    // A:0..49151(3 slots) B:49152..(2 slots)

    const int tid = threadIdx.x;
    const int bid = blockIdx.x;
    const int comp = bid & 7;          // (nt,h) == XCD: W panel (2 MB) L2-pinned
    const int nt = comp >> 1;          // 0..3
    const int h  = comp & 1;           // K half (experts 0-3 / 4-7)
    const int mt = bid >> 3;           // 0..31
    const int mbase = mt * 256;
    const int nbase = nt * 256;
    const int kofs = h * 4096;

    const int w  = tid >> 6;           // wave 0..7 (2M x 4N), wave tile 128x64
    const int l  = tid & 63;
    const int lr = l & 15;
    const int lg = l >> 4;
    const int wrow = (w >> 2) * 128;
    const int wcol = (w & 3) * 64;

    // staging lane coords: chunk = 16 rows x 32 cols bf16 = 1024 B
    const int lrow = l >> 2;
    const int sg = (l & 3) ^ ((l >> 3) & 3);     // pre-swizzled col block (involution)
    const int swz = (lr >> 1) & 3;

    // fragment read offsets within a slot (ushort units), matching XOR involution
    int aoff[8][2], boff[4][2];
#pragma unroll
    for (int mf = 0; mf < 8; ++mf)
#pragma unroll
        for (int ks = 0; ks < 2; ++ks)
            aoff[mf][ks] = ks * 8192 + (wrow + mf * 16 + lr) * 32 + ((lg ^ swz) * 8);
#pragma unroll
    for (int nf = 0; nf < 4; ++nf)
#pragma unroll
        for (int ks = 0; ks < 2; ++ks)
            boff[nf][ks] = ks * 8192 + (wcol + nf * 16 + lr) * 32 + ((lg ^ swz) * 8);

    // A staging (waves 0-3): 8 chunks/tile each, ids 0..31 over the wave group
    auto stageA4 = [&](int slot3, int kt, int half) {
#pragma unroll
        for (int i = 0; i < 4; ++i) {
            const int id = w * 8 + half * 4 + i;       // 0..31
            const int ks = id >> 4, sub = id & 15;
            const int kcb = kofs + kt * 64 + ks * 32 + sg * 8;
            gload16(Ap + (size_t)(mbase + sub * 16 + lrow) * (KEXP * INDIM) + kcb,
                    &lds[slot3 * 16384 + id * 512]);
        }
    };
    // B staging (waves 4-7): 8 chunks/tile each, ids 0..31 over the wave group
    auto stageB4 = [&](int slot2, int kt, int half) {
#pragma unroll
        for (int i = 0; i < 4; ++i) {
            const int id = (w - 4) * 8 + half * 4 + i; // 0..31
            const int ks = id >> 4, sub = id & 15;
            const int kcb = kofs + kt * 64 + ks * 32 + sg * 8;
            gload16(Wp + (size_t)(kcb >> 10) * (NDIM * INDIM)
                       + (size_t)(nbase + sub * 16 + lrow) * INDIM + (kcb & 1023),
                    &lds[49152 + slot2 * 16384 + id * 512]);
        }
    };

    f32x4 acc[8][4];
#pragma unroll
    for (int mf = 0; mf < 8; ++mf)
#pragma unroll
        for (int nf = 0; nf < 4; ++nf) acc[mf][nf] = f32x4{0.f, 0.f, 0.f, 0.f};

    // prologue: A dist-2 (tiles 0,1), B dist-1 (tile 0)
    if (w < 4) {
        stageA4(0, 0, 0); stageA4(0, 0, 1);
        stageA4(1, 1, 0); stageA4(1, 1, 1);
    } else {
        stageB4(0, 0, 0); stageB4(0, 0, 1);
    }

    int sA = 0, sA2 = 2;                 // sA = kt%3 (read), sA2 = (kt+2)%3 (stage)
#pragma unroll 1
    for (int kt = 0; kt < 64; ++kt) {
        const int cs = kt & 1;

        // gate: A-waves leave A(kt+1)'s 8 loads in flight (counted); B-waves and
        // the final A-tile drain fully. Barrier publishes all staging.
        if (w < 4 && kt < 63)
            asm volatile("s_waitcnt vmcnt(8)\n\ts_barrier" ::: "memory");
        else
            asm volatile("s_waitcnt vmcnt(0)\n\ts_barrier" ::: "memory");

        const unsigned short* lbA = &lds[sA * 16384];
        const unsigned short* lbB = &lds[49152 + cs * 16384];
        short8 alo[4], ahi[4], b0[4], b1[4];

        // q0 operands + first staging batch + q1 A-frags (drain under q0 MFMA)
#pragma unroll
        for (int m = 0; m < 4; ++m) alo[m] = *(const short8*)(lbA + aoff[m][0]);
#pragma unroll
        for (int n = 0; n < 4; ++n) b0[n] = *(const short8*)(lbB + boff[n][0]);
        if (w < 4) { if (kt + 2 < 64) stageA4(sA2, kt + 2, 0); }
        else       { if (kt + 1 < 64) stageB4(cs ^ 1, kt + 1, 0); }
#pragma unroll
        for (int m = 0; m < 4; ++m) ahi[m] = *(const short8*)(lbA + aoff[4 + m][0]);

        __builtin_amdgcn_s_setprio(1);
#pragma unroll
        for (int m = 0; m < 4; ++m)
#pragma unroll
            for (int n = 0; n < 4; ++n)
                acc[m][n] = __builtin_amdgcn_mfma_f32_16x16x32_bf16(alo[m], b0[n], acc[m][n], 0, 0, 0);
        __builtin_amdgcn_s_setprio(0);

        // q2 operands (ks1) issued now; second staging batch
#pragma unroll
        for (int n = 0; n < 4; ++n) b1[n] = *(const short8*)(lbB + boff[n][1]);
#pragma unroll
        for (int m = 0; m < 4; ++m) alo[m] = *(const short8*)(lbA + aoff[m][1]);
        if (w < 4) { if (kt + 2 < 64) stageA4(sA2, kt + 2, 1); }
        else       { if (kt + 1 < 64) stageB4(cs ^ 1, kt + 1, 1); }

        __builtin_amdgcn_s_setprio(1);
#pragma unroll
        for (int m = 0; m < 4; ++m)
#pragma unroll
            for (int n = 0; n < 4; ++n)
                acc[4 + m][n] = __builtin_amdgcn_mfma_f32_16x16x32_bf16(ahi[m], b0[n], acc[4 + m][n], 0, 0, 0);
        __builtin_amdgcn_s_setprio(0);

#pragma unroll
        for (int m = 0; m < 4; ++m) ahi[m] = *(const short8*)(lbA + aoff[4 + m][1]);

        __builtin_amdgcn_s_setprio(1);
#pragma unroll
        for (int m = 0; m < 4; ++m)
#pragma unroll
            for (int n = 0; n < 4; ++n)
                acc[m][n] = __builtin_amdgcn_mfma_f32_16x16x32_bf16(alo[m], b1[n], acc[m][n], 0, 0, 0);
        __builtin_amdgcn_s_setprio(0);

        __builtin_amdgcn_s_setprio(1);
#pragma unroll
        for (int m = 0; m < 4; ++m)
#pragma unroll
            for (int n = 0; n < 4; ++n)
                acc[4 + m][n] = __builtin_amdgcn_mfma_f32_16x16x32_bf16(ahi[m], b1[n], acc[4 + m][n], 0, 0, 0);
        __builtin_amdgcn_s_setprio(0);

        sA  = (sA  == 2) ? 0 : sA  + 1;
        sA2 = (sA2 == 2) ? 0 : sA2 + 1;
    }

    // epilogue: bf16 partial store
#pragma unroll
    for (int mf = 0; mf < 8; ++mf)
#pragma unroll
        for (int j = 0; j < 4; ++j) {
            const int grow = mbase + wrow + mf * 16 + lg * 4 + j;
            unsigned short* op = Pp + (size_t)h * NPH + (size_t)grow * NDIM + nbase + wcol;
#pragma unroll
            for (int nf = 0; nf < 4; ++nf) {
                union { __hip_bfloat16 hh; unsigned short u; } cv;
                cv.hh = __float2bfloat16(acc[mf][nf][j]);
                op[nf * 16 + lr] = cv.u;
            }
        }
}

// out = P0 + P1 + ew @ bias   (exact f32 blend of the two K-halves + bias)
__global__ void reduce_blend(const unsigned short* __restrict__ Pp,
                             const float* __restrict__ ew,
                             const float* __restrict__ bias,
                             float* __restrict__ out) {
    const long base = ((long)blockIdx.x * blockDim.x + threadIdx.x) * 8;
    if (base >= NPH) return;
    const int b = (int)(base >> 10);
    const int o = (int)(base & 1023);
    const short8 p0 = *(const short8*)(Pp + base);
    const short8 p1 = *(const short8*)(Pp + NPH + base);
    const float4 ea = *(const float4*)(ew + (size_t)b * KEXP);
    const float4 e2 = *(const float4*)(ew + (size_t)b * KEXP + 4);
    const float e[8] = {ea.x, ea.y, ea.z, ea.w, e2.x, e2.y, e2.z, e2.w};
    float r[8];
#pragma unroll
    for (int j = 0; j < 8; ++j)
        r[j] = bf2f((unsigned short)p0[j]) + bf2f((unsigned short)p1[j]);
#pragma unroll
    for (int k = 0; k < 8; ++k)
#pragma unroll
        for (int j = 0; j < 8; ++j) r[j] += e[k] * bias[k * NDIM + o + j];
    *(float4*)(out + base) = make_float4(r[0], r[1], r[2], r[3]);
    *(float4*)(out + base + 4) = make_float4(r[4], r[5], r[6], r[7]);
}

// ============ path B fallback: round-4 pipeline (ws >= 33.5 MB) ============

#define BM 256
#define BN 128
#define BK 64
#define NT 128
#define ABUF 16384
#define BBUF 8192
#define BUFU (ABUF + BBUF)

__global__ void convert_bf16(const float* __restrict__ x, const float* __restrict__ w,
                             unsigned short* __restrict__ dst) {
    const long total = (long)NX + NW;
    const long stride = (long)gridDim.x * blockDim.x * 8;
    for (long i = ((long)blockIdx.x * blockDim.x + threadIdx.x) * 8; i < total; i += stride) {
        const float* s = (i < NX) ? (x + i) : (w + (i - NX));
        float4 a = ((const float4*)s)[0];
        float4 b = ((const float4*)s)[1];
        uint4 q;
        q.x = pack2bf(a.x, a.y); q.y = pack2bf(a.z, a.w);
        q.z = pack2bf(b.x, b.y); q.w = pack2bf(b.z, b.w);
        *(uint4*)(dst + i) = q;
    }
}

__global__ __launch_bounds__(512, 2)
void moe_gemm_pipe(const unsigned short* __restrict__ ab,
                   const float* __restrict__ ew,
                   const float* __restrict__ bias,
                   float* __restrict__ out) {
    __shared__ __align__(16) unsigned short lds[3 * BUFU];

    const int tid = threadIdx.x;
    const int bid = blockIdx.x;
    const int nt = bid & 7;
    const int mt = bid >> 3;
    const int mbase = mt * BM;
    const int nbase = nt * BN;

    const int w  = tid >> 6;
    const int l  = tid & 63;
    const int lr = l & 15;
    const int lg = l >> 4;
    const int wrow = (w >> 1) * 64;
    const int wcol = (w & 1) * 64;

    const int lrow = l >> 2;
    const int sg = (l & 3) ^ ((l >> 3) & 3);

    const unsigned short* Xb = ab;
    const unsigned short* Wb = ab + NX;

    const int swz = (lr >> 1) & 3;
    int aoff[4][2], boff[4][2];
#pragma unroll
    for (int m = 0; m < 4; ++m)
#pragma unroll
        for (int ks = 0; ks < 2; ++ks)
            aoff[m][ks] = ks * 8192 + (wrow + m * 16 + lr) * 32 + ((lg ^ swz) * 8);
#pragma unroll
    for (int n = 0; n < 4; ++n)
#pragma unroll
        for (int ks = 0; ks < 2; ++ks)
            boff[n][ks] = ABUF + ks * 4096 + (wcol + n * 16 + lr) * 32 + ((lg ^ swz) * 8);

    auto stageA = [&](int buf, int kt, int i) {
        const int c = i * 8 + w;
        const int ks = c >> 4, rg = c & 15;
        const unsigned short* src = Xb + (size_t)(mbase + rg * 16 + lrow) * INDIM
                                  + (size_t)((kt & 15) * 64 + ks * 32 + sg * 8);
        gload16(src, &lds[buf * BUFU + c * 512]);
    };
    auto stageB = [&](int buf, int kt, int i) {
        const int c = i * 8 + w;
        const int ks = c >> 3, rg = c & 7;
        const unsigned short* src = Wb + (size_t)(kt >> 4) * (NDIM * INDIM)
                                  + (size_t)(nbase + rg * 16 + lrow) * INDIM
                                  + (size_t)((kt & 15) * 64 + ks * 32 + sg * 8);
        gload16(src, &lds[buf * BUFU + ABUF + c * 512]);
    };

    f32x4 acc[4][4], accT[4][4];
#pragma unroll
    for (int m = 0; m < 4; ++m)
#pragma unroll
        for (int n = 0; n < 4; ++n) {
            acc[m][n] = f32x4{0.f, 0.f, 0.f, 0.f};
            accT[m][n] = f32x4{0.f, 0.f, 0.f, 0.f};
        }

#pragma unroll
    for (int t = 0; t < 2; ++t) {
        stageA(t, t, 0); stageA(t, t, 1); stageA(t, t, 2); stageA(t, t, 3);
        stageB(t, t, 0); stageB(t, t, 1);
    }

    int bufR = 0, bufS = 2;
#pragma unroll 1
    for (int kt = 0; kt < NT; ++kt) {
        const bool doS = (kt + 2) < NT;
        const bool bnd = (kt & 15) == 15;

        if (kt < NT - 2)
            asm volatile("s_waitcnt vmcnt(6)\n\ts_barrier" ::: "memory");
        else
            asm volatile("s_waitcnt vmcnt(0)\n\ts_barrier" ::: "memory");

        float e0[4][4];
        if (bnd) {
            const int eidx = kt >> 4;
#pragma unroll
            for (int m = 0; m < 4; ++m)
#pragma unroll
                for (int j = 0; j < 4; ++j)
                    e0[m][j] = ew[(size_t)(mbase + wrow + m * 16 + lg * 4 + j) * KEXP + eidx];
        }

        const unsigned short* lb = &lds[bufR * BUFU];
        short8 a0[4], b0[4], a1[4], b1[4];
#pragma unroll
        for (int m = 0; m < 4; ++m) a0[m] = *(const short8*)(lb + aoff[m][0]);
#pragma unroll
        for (int n = 0; n < 4; ++n) b0[n] = *(const short8*)(lb + boff[n][0]);
        if (doS) {
            stageA(bufS, kt + 2, 0); stageA(bufS, kt + 2, 1);
            stageA(bufS, kt + 2, 2); stageA(bufS, kt + 2, 3);
            stageB(bufS, kt + 2, 0); stageB(bufS, kt + 2, 1);
        }
#pragma unroll
        for (int m = 0; m < 4; ++m) a1[m] = *(const short8*)(lb + aoff[m][1]);
#pragma unroll
        for (int n = 0; n < 4; ++n) b1[n] = *(const short8*)(lb + boff[n][1]);

        __builtin_amdgcn_s_setprio(1);
#pragma unroll
        for (int m = 0; m < 4; ++m)
#pragma unroll
            for (int n = 0; n < 4; ++n)
                acc[m][n] = __builtin_amdgcn_mfma_f32_16x16x32_bf16(a0[m], b0[n], acc[m][n], 0, 0, 0);
        __builtin_amdgcn_s_setprio(0);
        __builtin_amdgcn_s_setprio(1);
#pragma unroll
        for (int m = 0; m < 4; ++m)
#pragma unroll
            for (int n = 0; n < 4; ++n)
                acc[m][n] = __builtin_amdgcn_mfma_f32_16x16x32_bf16(a1[m], b1[n], acc[m][n], 0, 0, 0);
        __builtin_amdgcn_s_setprio(0);

        if (bnd) {
#pragma unroll
            for (int m = 0; m < 4; ++m)
#pragma unroll
                for (int n = 0; n < 4; ++n) {
#pragma unroll
                    for (int j = 0; j < 4; ++j)
                        accT[m][n][j] += e0[m][j] * acc[m][n][j];
                    acc[m][n] = f32x4{0.f, 0.f, 0.f, 0.f};
                }
        }

        bufR = (bufR == 2) ? 0 : bufR + 1;
        bufS = (bufS == 2) ? 0 : bufS + 1;
    }

    float bv[4][8];
#pragma unroll
    for (int n = 0; n < 4; ++n) {
        const int gc = nbase + wcol + n * 16 + lr;
#pragma unroll
        for (int kk = 0; kk < 8; ++kk) bv[n][kk] = bias[kk * NDIM + gc];
    }
#pragma unroll
    for (int m = 0; m < 4; ++m)
#pragma unroll
        for (int j = 0; j < 4; ++j) {
            const int grow = mbase + wrow + m * 16 + lg * 4 + j;
            const float4* e4 = (const float4*)(ew + (size_t)grow * KEXP);
            const float4 ea = e4[0];
            const float4 eb = e4[1];
            const float ev[8] = {ea.x, ea.y, ea.z, ea.w, eb.x, eb.y, eb.z, eb.w};
            float* op = out + (size_t)grow * NDIM + nbase + wcol;
#pragma unroll
            for (int n = 0; n < 4; ++n) {
                float t = accT[m][n][j];
#pragma unroll
                for (int kk = 0; kk < 8; ++kk) t += ev[kk] * bv[n][kk];
                op[n * 16 + lr] = t;
            }
        }
}

extern "C" void kernel_launch(void* const* d_in, const int* in_sizes, int n_in,
                              void* d_out, int out_size, void* d_ws, size_t ws_size,
                              hipStream_t stream) {
    (void)in_sizes; (void)n_in; (void)out_size;
    const float* x    = (const float*)d_in[0];
    const float* ew   = (const float*)d_in[1];
    const float* w    = (const float*)d_in[2];
    const float* bias = (const float*)d_in[3];
    float* out = (float*)d_out;

    const size_t needA = ((size_t)NA + NW + 2 * (size_t)NPH) * sizeof(unsigned short); // 184.5 MB
    const size_t needB = (size_t)(NX + NW) * sizeof(unsigned short);                   // 33.5 MB

    if (ws_size >= needA) {
        unsigned short* Ap = (unsigned short*)d_ws;
        unsigned short* Wp = Ap + NA;
        unsigned short* Pp = Wp + NW;
        hipLaunchKernelGGL(convert_aw, dim3(8192), dim3(256), 0, stream, x, ew, w, Ap, Wp);
        hipLaunchKernelGGL(moe_gemm_ks4, dim3(256), dim3(512), 0, stream, Ap, Wp, Pp);
        hipLaunchKernelGGL(reduce_blend, dim3(4096), dim3(256), 0, stream, Pp, ew, bias, out);
    } else if (ws_size >= needB) {
        unsigned short* ab = (unsigned short*)d_ws;
        hipLaunchKernelGGL(convert_bf16, dim3(4096), dim3(256), 0, stream, x, w, ab);
        hipLaunchKernelGGL(moe_gemm_pipe, dim3(256), dim3(512), 0, stream, ab, ew, bias, out);
    }
}

// Round 12
// 145.857 us; speedup vs baseline: 1.5641x; 1.1180x over previous
//
#include <hip/hip_runtime.h>
#include <hip/hip_bf16.h>

typedef __attribute__((ext_vector_type(8))) short short8;
typedef __attribute__((ext_vector_type(4))) float f32x4;

#define NDIM 1024
#define INDIM 1024
#define KEXP 8
#define BROWS 8192
#define NX (BROWS * INDIM)        // x elements   8388608
#define NW (KEXP * NDIM * INDIM)  // w elements   8388608

__device__ __forceinline__ unsigned int pack2bf(float a, float b) {
    __hip_bfloat162 h = __float22bfloat162_rn(make_float2(a, b));
    union { __hip_bfloat162 h; unsigned int u; } cv;
    cv.h = h;
    return cv.u;
}

__device__ __forceinline__ void gload16(const void* src, void* ldsdst) {
    __builtin_amdgcn_global_load_lds(
        (__attribute__((address_space(1))) void*)(src),
        (__attribute__((address_space(3))) void*)(ldsdst), 16, 0, 0);
}

// convert: ws = [bf16(x) | bf16(w)] contiguous
__global__ void convert_bf16(const float* __restrict__ x, const float* __restrict__ w,
                             unsigned short* __restrict__ dst) {
    const long total = (long)NX + NW;
    const long stride = (long)gridDim.x * blockDim.x * 8;
    for (long i = ((long)blockIdx.x * blockDim.x + threadIdx.x) * 8; i < total; i += stride) {
        const float* s = (i < NX) ? (x + i) : (w + (i - NX));
        float4 a = ((const float4*)s)[0];
        float4 b = ((const float4*)s)[1];
        uint4 q;
        q.x = pack2bf(a.x, a.y); q.y = pack2bf(a.z, a.w);
        q.z = pack2bf(b.x, b.y); q.w = pack2bf(b.z, b.w);
        *(uint4*)(dst + i) = q;
    }
}

// Transposed-M fused GEMM+blend. M = gathered (o,k): block tile = 32 o x 8 experts
// = 256 rows (g = (o-o0)*8 + k, so ke = lrow&7 per-lane-constant in staging).
// C[g,b] = sum_i W[ke,o,i]*x[b,i]; epilogue does the k-blend in f32 (4 FMA +
// shfl_xor(16) per frag), LDS-transposes, adds exact ew@bias, stores f32 out.
// Schedule/geometry = r5's verified kernel: 256x256, BK=64, 8 waves of 128x64,
// dbuf-2 LDS, vmcnt(0)+barrier gate per tile, XOR-swizzled staging.
__global__ __launch_bounds__(512, 2)
void moe_gemm_fold(const unsigned short* __restrict__ xb,   // [8192][1024] bf16
                   const float* __restrict__ ew,            // [8192][8]
                   const unsigned short* __restrict__ Wp,   // [8][1024][1024] bf16
                   const float* __restrict__ bias,          // [8][1024]
                   float* __restrict__ out) {               // [8192][1024] f32
    __shared__ __align__(16) unsigned short lds[2 * 32768];   // 128 KiB dbuf

    const int tid = threadIdx.x;
    const int bid = blockIdx.x;
    // XCD-pinned x-slices: xcd = bid&7 owns 4 b-tiles (2 MB x) L2-resident
    const int xcd = bid & 7;
    const int grp = bid >> 3;              // 0..127
    const int bt = xcd * 4 + (grp & 3);    // 0..31  b-tile
    const int ot = grp >> 2;               // 0..31  o-tile
    const int bbase = bt * 256;
    const int o_blk = ot * 32;

    const int w  = tid >> 6;           // wave 0..7 (2M x 4N), wave tile 128x64
    const int l  = tid & 63;
    const int lr = l & 15;
    const int lg = l >> 4;
    const int wrow = (w >> 2) * 128;
    const int wcol = (w & 3) * 64;

    // staging lane coords: chunk = 16 rows x 32 cols bf16 = 1024 B
    const int lrow = l >> 2;
    const int sg = (l & 3) ^ ((l >> 3) & 3);     // pre-swizzled col block (involution)
    const int swz = (lr >> 1) & 3;

    // fragment read offsets (ushort units), matching XOR involution
    int aoff[8][2], boff[4][2];
#pragma unroll
    for (int mf = 0; mf < 8; ++mf)
#pragma unroll
        for (int ks = 0; ks < 2; ++ks)
            aoff[mf][ks] = ks * 8192 + (wrow + mf * 16 + lr) * 32 + ((lg ^ swz) * 8);
#pragma unroll
    for (int nf = 0; nf < 4; ++nf)
#pragma unroll
        for (int ks = 0; ks < 2; ++ks)
            boff[nf][ks] = 16384 + ks * 8192 + (wcol + nf * 16 + lr) * 32 + ((lg ^ swz) * 8);

    // staging: 64 chunks/tile (A=W-gather ids 0-31, B=x ids 32-63), wave w owns 8
    auto stage4 = [&](int slot, int kt, int half) {
#pragma unroll
        for (int i = 0; i < 4; ++i) {
            const int id = w * 8 + half * 4 + i;
            unsigned short* dst = &lds[slot * 32768 + id * 512];
            const int sub = id & 15;
            const int col = kt * 64 + ((id >> 4) & 1) * 32 + sg * 8;
            if (id < 32) {
                // gathered row g = sub*16 + lrow: ke = lrow&7, o = o_blk + sub*2 + (lrow>>3)
                gload16(Wp + (size_t)(lrow & 7) * (NDIM * INDIM)
                           + (size_t)(o_blk + sub * 2 + (lrow >> 3)) * INDIM + col, dst);
            } else {
                gload16(xb + (size_t)(bbase + sub * 16 + lrow) * INDIM + col, dst);
            }
        }
    };

    f32x4 acc[8][4];
#pragma unroll
    for (int mf = 0; mf < 8; ++mf)
#pragma unroll
        for (int nf = 0; nf < 4; ++nf) acc[mf][nf] = f32x4{0.f, 0.f, 0.f, 0.f};

    stage4(0, 0, 0);
    stage4(0, 0, 1);

#pragma unroll 1
    for (int kt = 0; kt < 16; ++kt) {
        const int cs = kt & 1;
        const bool doS = (kt + 1) < 16;

        // tile gate: stage(kt) landed; barrier publishes all waves' staging.
        asm volatile("s_waitcnt vmcnt(0)\n\ts_barrier" ::: "memory");

        const unsigned short* lb = &lds[cs * 32768];
        short8 alo[4], ahi[4], b0[4], b1[4];

        // q0 operands + first staging batch + q1 A-frags (drain under q0 MFMA)
#pragma unroll
        for (int m = 0; m < 4; ++m) alo[m] = *(const short8*)(lb + aoff[m][0]);
#pragma unroll
        for (int n = 0; n < 4; ++n) b0[n] = *(const short8*)(lb + boff[n][0]);
        if (doS) stage4(cs ^ 1, kt + 1, 0);
#pragma unroll
        for (int m = 0; m < 4; ++m) ahi[m] = *(const short8*)(lb + aoff[4 + m][0]);

        __builtin_amdgcn_s_setprio(1);
#pragma unroll
        for (int m = 0; m < 4; ++m)
#pragma unroll
            for (int n = 0; n < 4; ++n)
                acc[m][n] = __builtin_amdgcn_mfma_f32_16x16x32_bf16(alo[m], b0[n], acc[m][n], 0, 0, 0);
        __builtin_amdgcn_s_setprio(0);

        // q2 operands (ks1) issued now; second staging batch
#pragma unroll
        for (int n = 0; n < 4; ++n) b1[n] = *(const short8*)(lb + boff[n][1]);
#pragma unroll
        for (int m = 0; m < 4; ++m) alo[m] = *(const short8*)(lb + aoff[m][1]);
        if (doS) stage4(cs ^ 1, kt + 1, 1);

        __builtin_amdgcn_s_setprio(1);
#pragma unroll
        for (int m = 0; m < 4; ++m)
#pragma unroll
            for (int n = 0; n < 4; ++n)
                acc[4 + m][n] = __builtin_amdgcn_mfma_f32_16x16x32_bf16(ahi[m], b0[n], acc[4 + m][n], 0, 0, 0);
        __builtin_amdgcn_s_setprio(0);

#pragma unroll
        for (int m = 0; m < 4; ++m) ahi[m] = *(const short8*)(lb + aoff[4 + m][1]);

        __builtin_amdgcn_s_setprio(1);
#pragma unroll
        for (int m = 0; m < 4; ++m)
#pragma unroll
            for (int n = 0; n < 4; ++n)
                acc[m][n] = __builtin_amdgcn_mfma_f32_16x16x32_bf16(alo[m], b1[n], acc[m][n], 0, 0, 0);
        __builtin_amdgcn_s_setprio(0);

        __builtin_amdgcn_s_setprio(1);
#pragma unroll
        for (int m = 0; m < 4; ++m)
#pragma unroll
            for (int n = 0; n < 4; ++n)
                acc[4 + m][n] = __builtin_amdgcn_mfma_f32_16x16x32_bf16(ahi[m], b1[n], acc[4 + m][n], 0, 0, 0);
        __builtin_amdgcn_s_setprio(0);
    }

    // ---- epilogue: per-frag k-blend (f32) -> LDS transpose -> coalesced store ----
    // C/D map: frag row = lg*4 + j -> g = wrow + mf*16 + lg*4 + j
    //          -> o = o_blk + (g>>3), k = g&7 = (lg&1)*4 + j (since wrow,16|g base)
    __syncthreads();                       // staging consumed; reuse LDS
    float* ylds = (float*)lds;             // [256 b][36] f32 (144 B rows, 16-aligned)

    const int obw = wrow >> 3;             // wave o-offset: 0 or 16
#pragma unroll
    for (int nf = 0; nf < 4; ++nf) {
        const int bl = wcol + nf * 16 + lr;          // block-local b
        const float4 ea = *(const float4*)(ew + (size_t)(bbase + bl) * KEXP);
        const float4 eb = *(const float4*)(ew + (size_t)(bbase + bl) * KEXP + 4);
        float c0, c1, c2, c3;
        if (lg & 1) { c0 = eb.x; c1 = eb.y; c2 = eb.z; c3 = eb.w; }
        else        { c0 = ea.x; c1 = ea.y; c2 = ea.z; c3 = ea.w; }
#pragma unroll
        for (int mf = 0; mf < 8; ++mf) {
            float p = c0 * acc[mf][nf][0] + c1 * acc[mf][nf][1]
                    + c2 * acc[mf][nf][2] + c3 * acc[mf][nf][3];
            p += __shfl_xor(p, 16);                  // sum k 0-3 with k 4-7
            if (!(lg & 1))
                ylds[bl * 36 + obw + mf * 2 + (lg >> 1)] = p;
        }
    }
    __syncthreads();

    {   // coalesced f32 store + exact ew@bias
        const int b = tid >> 1;
        const int oh = (tid & 1) * 16;
        const float* yr = &ylds[b * 36 + oh];
        float y0[16];
#pragma unroll
        for (int jj = 0; jj < 16; ++jj) y0[jj] = yr[jj];
        const float4 ea = *(const float4*)(ew + (size_t)(bbase + b) * KEXP);
        const float4 e2 = *(const float4*)(ew + (size_t)(bbase + b) * KEXP + 4);
        const float ekk[8] = {ea.x, ea.y, ea.z, ea.w, e2.x, e2.y, e2.z, e2.w};
#pragma unroll
        for (int k = 0; k < 8; ++k) {
            const float* bp = bias + k * NDIM + o_blk + oh;
#pragma unroll
            for (int jj = 0; jj < 16; ++jj) y0[jj] += ekk[k] * bp[jj];
        }
        float* op = out + (size_t)(bbase + b) * NDIM + o_blk + oh;
#pragma unroll
        for (int jj = 0; jj < 4; ++jj)
            *(float4*)(op + jj * 4) =
                make_float4(y0[jj * 4], y0[jj * 4 + 1], y0[jj * 4 + 2], y0[jj * 4 + 3]);
    }
}

// ---------------- fallback (round-1 kernel, needs NO workspace) ----------------
#define FLDW 40
__global__ __launch_bounds__(256, 2)
void moe_blend_gemm_fb(const float* __restrict__ x, const float* __restrict__ ew,
                       const float* __restrict__ w, const float* __restrict__ bias,
                       float* __restrict__ out) {
    __shared__ unsigned short lA[128][FLDW];
    __shared__ unsigned short lB[128][FLDW];
    const int tid = threadIdx.x, bid = blockIdx.x;
    const int nt = bid & 7, mt = bid >> 3;
    const int mbase = mt * 128, nbase = nt * 128;
    const int trow = tid >> 1, tcol = (tid & 1) * 16;
    const float* xp = x + (size_t)(mbase + trow) * INDIM + tcol;
    const float* wp = w + (size_t)(nbase + trow) * INDIM + tcol;
    const float* ep = ew + (size_t)(mbase + trow) * KEXP;
    const int wid = tid >> 6, wrB = (wid >> 1) * 64, wcB = (wid & 1) * 64;
    const int l = tid & 63, lr = l & 15, lg = l >> 4;
    f32x4 acc[4][4];
#pragma unroll
    for (int m = 0; m < 4; ++m)
#pragma unroll
        for (int n = 0; n < 4; ++n) acc[m][n] = f32x4{0.f, 0.f, 0.f, 0.f};
    const unsigned short* rdA = &lA[wrB + lr][lg * 8];
    const unsigned short* rdB = &lB[wcB + lr][lg * 8];
    unsigned int* wA = (unsigned int*)&lA[trow][tcol];
    unsigned int* wB = (unsigned int*)&lB[trow][tcol];
    float4 ra0, ra1, ra2, ra3, rb0, rb1, rb2, rb3;
    float sc;
    {
        const float4* pa = (const float4*)(xp);
        ra0 = pa[0]; ra1 = pa[1]; ra2 = pa[2]; ra3 = pa[3];
        const float4* pb = (const float4*)(wp);
        rb0 = pb[0]; rb1 = pb[1]; rb2 = pb[2]; rb3 = pb[3];
        sc = ep[0];
    }
    for (int tt = 0; tt < 256; ++tt) {
        __syncthreads();
        uint4 qa0, qa1, qb0, qb1;
        qa0.x = pack2bf(ra0.x * sc, ra0.y * sc); qa0.y = pack2bf(ra0.z * sc, ra0.w * sc);
        qa0.z = pack2bf(ra1.x * sc, ra1.y * sc); qa0.w = pack2bf(ra1.z * sc, ra1.w * sc);
        qa1.x = pack2bf(ra2.x * sc, ra2.y * sc); qa1.y = pack2bf(ra2.z * sc, ra2.w * sc);
        qa1.z = pack2bf(ra3.x * sc, ra3.y * sc); qa1.w = pack2bf(ra3.z * sc, ra3.w * sc);
        qb0.x = pack2bf(rb0.x, rb0.y); qb0.y = pack2bf(rb0.z, rb0.w);
        qb0.z = pack2bf(rb1.x, rb1.y); qb0.w = pack2bf(rb1.z, rb1.w);
        qb1.x = pack2bf(rb2.x, rb2.y); qb1.y = pack2bf(rb2.z, rb2.w);
        qb1.z = pack2bf(rb3.x, rb3.y); qb1.w = pack2bf(rb3.z, rb3.w);
        *(uint4*)(wA) = qa0; *(uint4*)(wA + 4) = qa1;
        *(uint4*)(wB) = qb0; *(uint4*)(wB + 4) = qb1;
        __syncthreads();
        if (tt + 1 < 256) {
            const int kc = (tt + 1) >> 5, i0 = ((tt + 1) & 31) * 32;
            const float4* pa = (const float4*)(xp + i0);
            ra0 = pa[0]; ra1 = pa[1]; ra2 = pa[2]; ra3 = pa[3];
            const float4* pb = (const float4*)(wp + (size_t)kc * (size_t)(NDIM * INDIM) + i0);
            rb0 = pb[0]; rb1 = pb[1]; rb2 = pb[2]; rb3 = pb[3];
            sc = ep[kc];
        }
        short8 af[4], bf[4];
#pragma unroll
        for (int m = 0; m < 4; ++m) af[m] = *(const short8*)(rdA + m * 16 * FLDW);
#pragma unroll
        for (int n = 0; n < 4; ++n) bf[n] = *(const short8*)(rdB + n * 16 * FLDW);
#pragma unroll
        for (int m = 0; m < 4; ++m)
#pragma unroll
            for (int n = 0; n < 4; ++n)
                acc[m][n] = __builtin_amdgcn_mfma_f32_16x16x32_bf16(af[m], bf[n], acc[m][n], 0, 0, 0);
    }
#pragma unroll
    for (int m = 0; m < 4; ++m)
#pragma unroll
        for (int j = 0; j < 4; ++j) {
            const int gr = mbase + wrB + m * 16 + lg * 4 + j;
            const float4* e4 = (const float4*)(ew + (size_t)gr * KEXP);
            const float4 e0 = e4[0], e1 = e4[1];
            const float eb[8] = {e0.x, e0.y, e0.z, e0.w, e1.x, e1.y, e1.z, e1.w};
            float* op = out + (size_t)gr * NDIM + nbase + wcB;
#pragma unroll
            for (int n = 0; n < 4; ++n) {
                float t = acc[m][n][j];
#pragma unroll
                for (int kk = 0; kk < 8; ++kk) t += eb[kk] * bias[kk * NDIM + nbase + wcB + n * 16 + lr];
                op[n * 16 + lr] = t;
            }
        }
}

extern "C" void kernel_launch(void* const* d_in, const int* in_sizes, int n_in,
                              void* d_out, int out_size, void* d_ws, size_t ws_size,
                              hipStream_t stream) {
    (void)in_sizes; (void)n_in; (void)out_size;
    const float* x    = (const float*)d_in[0];
    const float* ew   = (const float*)d_in[1];
    const float* w    = (const float*)d_in[2];
    const float* bias = (const float*)d_in[3];
    float* out = (float*)d_out;

    const size_t need = (size_t)(NX + NW) * sizeof(unsigned short);   // 33.5 MB

    if (ws_size >= need) {
        unsigned short* xb = (unsigned short*)d_ws;
        unsigned short* Wp = xb + NX;
        hipLaunchKernelGGL(convert_bf16, dim3(4096), dim3(256), 0, stream, x, w, xb);
        hipLaunchKernelGGL(moe_gemm_fold, dim3(1024), dim3(512), 0, stream, xb, ew, Wp, bias, out);
    } else {
        hipLaunchKernelGGL(moe_blend_gemm_fb, dim3(512), dim3(256), 0, stream, x, ew, w, bias, out);
    }
}